// Round 1
// baseline (831.988 us; speedup 1.0000x reference)
//
#include <hip/hip_runtime.h>
#include <stdint.h>

// NBMEHead: out[b,s,o] = sum_d avg[b,s,d] * W[o,d] + bias[o]
// avg = mean over 5 inverted-dropout passes, p = 0.1..0.5, JAX threefry PRNG,
// root dropout key = jax.random.key(42).
//
// PRNG scheme implemented: jax_threefry_partitionable = True (JAX >= 0.4.36
// default):
//   subkey_j   = threefry2x32((0,42), (0, j))            (fold-like split)
//   bits(i)    = v0 ^ v1 of threefry2x32(subkey_j, (0,i)) (i = flat elem idx)
//   keep       = ((bits>>9) * 2^-23) < float32(1-p)
//              = bits < (ceil(float32(1-p) * 2^23) << 9)   [exact]
// Fallback if this fails (old JAX, non-partitionable): split uses halved
// iota(10); bits(i) pairs (i, i+2^25) -> (v0, v1). Switch next round if absmax
// comes back O(1).

struct TF2 { uint32_t a, b; };

__host__ __device__ constexpr uint32_t rotl32(uint32_t x, int r) {
  return (x << r) | (x >> (32 - r));
}

// Threefry-2x32, 20 rounds, exactly as jax/_src/prng.py.
__host__ __device__ constexpr TF2 tf2x32(uint32_t k0, uint32_t k1,
                                         uint32_t x0, uint32_t x1) {
  const uint32_t ks2 = k0 ^ k1 ^ 0x1BD11BDAu;
  x0 += k0; x1 += k1;
#define TFR(r) { x0 += x1; x1 = rotl32(x1, (r)); x1 ^= x0; }
  TFR(13) TFR(15) TFR(26) TFR(6)
  x0 += k1;  x1 += ks2 + 1u;
  TFR(17) TFR(29) TFR(16) TFR(24)
  x0 += ks2; x1 += k0 + 2u;
  TFR(13) TFR(15) TFR(26) TFR(6)
  x0 += k0;  x1 += k1 + 3u;
  TFR(17) TFR(29) TFR(16) TFR(24)
  x0 += k1;  x1 += ks2 + 4u;
  TFR(13) TFR(15) TFR(26) TFR(6)
  x0 += ks2; x1 += k0 + 5u;
#undef TFR
  return TF2{x0, x1};
}

// Subkeys for the 5 dropout passes (fold-like split of key(42)).
// All compile-time constants -> key injections become literal adds.
constexpr TF2 SUBKEY[5] = {
  tf2x32(0u, 42u, 0u, 0u),
  tf2x32(0u, 42u, 0u, 1u),
  tf2x32(0u, 42u, 0u, 2u),
  tf2x32(0u, 42u, 0u, 3u),
  tf2x32(0u, 42u, 0u, 4u),
};

// keep iff bits < TS[j]  (pre-shifted integer threshold, exact equivalence
// with JAX's float compare since u = (bits>>9)*2^-23 is exact).
__host__ __device__ constexpr uint32_t keep_threshold(double p) {
  float q = (float)(1.0 - p);
  double v = (double)q * 8388608.0;  // q * 2^23
  uint32_t t = (uint32_t)v;
  if ((double)t < v) ++t;            // ceil
  return t << 9;
}
constexpr uint32_t TS[5] = {
  keep_threshold(0.1), keep_threshold(0.2), keep_threshold(0.3),
  keep_threshold(0.4), keep_threshold(0.5),
};

// per-pass weight: (1/(1-p))/5 folded into one multiplier
__host__ __device__ constexpr float keep_weight(double p) {
  float q = (float)(1.0 - p);
  return (float)(1.0 / ((double)q * 5.0));
}
constexpr float WJ[5] = {
  keep_weight(0.1), keep_weight(0.2), keep_weight(0.3),
  keep_weight(0.4), keep_weight(0.5),
};

// One block per (b,s) row of D=1024. 256 threads x 4 elements each.
// Grid = 32*2048 = 65536 blocks.
__global__ __launch_bounds__(256) void nbme_head_kernel(
    const float* __restrict__ x, const float* __restrict__ W,
    const float* __restrict__ bias, float* __restrict__ out) {
  const int row = blockIdx.x;          // b*2048 + s, in [0, 65536)
  const int tid = threadIdx.x;

  const uint32_t base = (uint32_t)row * 1024u + (uint32_t)(tid << 2);

  const float4 xv = ((const float4*)x)[row * 256 + tid];
  const float4 w0 = ((const float4*)(W))[tid];
  const float4 w1 = ((const float4*)(W + 1024))[tid];
  const float4 w2 = ((const float4*)(W + 2048))[tid];

  const float xs[4]  = {xv.x, xv.y, xv.z, xv.w};
  const float w0s[4] = {w0.x, w0.y, w0.z, w0.w};
  const float w1s[4] = {w1.x, w1.y, w1.z, w1.w};
  const float w2s[4] = {w2.x, w2.y, w2.z, w2.w};

  float acc0 = 0.f, acc1 = 0.f, acc2 = 0.f;

#pragma unroll
  for (int e = 0; e < 4; ++e) {
    const uint32_t i = base + (uint32_t)e;  // flat element index (< 2^26)
    float coef = 0.f;
#pragma unroll
    for (int j = 0; j < 5; ++j) {
      TF2 r = tf2x32(SUBKEY[j].a, SUBKEY[j].b, 0u, i);
      uint32_t bits = r.a ^ r.b;            // partitionable 32-bit draw
      coef += (bits < TS[j]) ? WJ[j] : 0.f;
    }
    const float v = xs[e] * coef;           // avg[b,s,d]
    acc0 = fmaf(v, w0s[e], acc0);
    acc1 = fmaf(v, w1s[e], acc1);
    acc2 = fmaf(v, w2s[e], acc2);
  }

  // wave64 shuffle reduction of the three partial dots
#pragma unroll
  for (int off = 32; off > 0; off >>= 1) {
    acc0 += __shfl_down(acc0, off);
    acc1 += __shfl_down(acc1, off);
    acc2 += __shfl_down(acc2, off);
  }

  __shared__ float smem[4][3];
  const int lane = tid & 63, wave = tid >> 6;
  if (lane == 0) {
    smem[wave][0] = acc0; smem[wave][1] = acc1; smem[wave][2] = acc2;
  }
  __syncthreads();
  if (tid < 3) {
    float s = smem[0][tid] + smem[1][tid] + smem[2][tid] + smem[3][tid]
            + bias[tid];
    out[row * 3 + tid] = s;
  }
}

extern "C" void kernel_launch(void* const* d_in, const int* in_sizes, int n_in,
                              void* d_out, int out_size, void* d_ws,
                              size_t ws_size, hipStream_t stream) {
  const float* x    = (const float*)d_in[0];  // [32,2048,1024]
  const float* W    = (const float*)d_in[1];  // [3,1024]
  const float* bias = (const float*)d_in[2];  // [3]
  float* out        = (float*)d_out;          // [32,2048,3]

  nbme_head_kernel<<<dim3(65536), dim3(256), 0, stream>>>(x, W, bias, out);
}